// Round 3
// baseline (603.485 us; speedup 1.0000x reference)
//
#include <hip/hip_runtime.h>
#include <hip/hip_cooperative_groups.h>
#include <math.h>

namespace cg = cooperative_groups;

#define M_TOTAL (32 * 8732)      // 279424 anchors
#define NTILES  (M_TOTAL / 64)   // 4366 tiles of 64 anchors
#define NBLK    512
#define NREP    4

// ---- workspace layout (bytes) ----
#define CON_B   ((size_t)0)
#define HISTR_B ((size_t)M_TOTAL * 4)
#define VSUMR_B (HISTR_B + (size_t)NREP * 2048 * 4)
#define H1C_B   (VSUMR_B + (size_t)NREP * 2048 * 4)
#define H1V_B   (H1C_B   + (size_t)NREP * 2048 * 4)
#define H2_B    (H1V_B   + (size_t)NREP * 2048 * 4)
#define PART_B  (H2_B    + (size_t)1024 * 4)
#define G_B     (PART_B  + (size_t)NBLK * 16)

struct GScal { unsigned b0; unsigned pref; };

__device__ __forceinline__ float smooth_l1(float d) {
    float ad = fabsf(d);
    return (ad < 1.0f) ? 0.5f * ad * ad : ad - 0.5f;
}

__device__ __forceinline__ void g_store_u(unsigned* p, unsigned v) {
    __hip_atomic_store(p, v, __ATOMIC_RELAXED, __HIP_MEMORY_SCOPE_AGENT);
}
__device__ __forceinline__ unsigned g_load_u(const unsigned* p) {
    return __hip_atomic_load(p, __ATOMIC_RELAXED, __HIP_MEMORY_SCOPE_AGENT);
}

#define GLLDS16(gp, lp) __builtin_amdgcn_global_load_lds( \
    (__attribute__((address_space(1))) void*)(gp),        \
    (__attribute__((address_space(3))) void*)(lp), 16, 0, 0)

// 256-thread suffix-select over nbins (256|512|1024|2048) bins held in LDS:
// finds bin with suffix(bin) >= k > suffix(bin+1), returns bin, k-suffix(bin+1),
// and sum of vsum[] over bins strictly above.
__device__ void selectk(const unsigned* cnt, const float* vsum, int nbins, unsigned k,
                        unsigned* ssum, float* wred, unsigned* bcb, unsigned* bck,
                        unsigned* out_bin, unsigned* out_k, float* out_sum) {
    const int t = threadIdx.x;
    const int chunk = nbins >> 8;
    if (t == 0) { *bcb = 0u; *bck = 0u; }
    unsigned tot = 0;
    for (int j = 0; j < chunk; ++j) tot += cnt[t * chunk + j];
    ssum[t] = tot;
    __syncthreads();
    for (int off = 1; off < 256; off <<= 1) {
        const unsigned val = ssum[t];
        const unsigned add = (t + off < 256) ? ssum[t + off] : 0u;
        __syncthreads();
        ssum[t] = val + add;
        __syncthreads();
    }
    const unsigned s_after = (t < 255) ? ssum[t + 1] : 0u;
    if (k > 0u && ssum[t] >= k && k > s_after) {
        unsigned cum = s_after;
        for (int j = chunk - 1; j >= 0; --j) {
            const unsigned bin = t * chunk + j;
            const unsigned nc = cum + cnt[bin];
            if (nc >= k) { *bcb = bin; *bck = k - cum; break; }
            cum = nc;
        }
    }
    __syncthreads();
    const unsigned b = *bcb;
    float sh = 0.f;
    for (int j = 0; j < chunk; ++j) {
        const unsigned bin = t * chunk + j;
        if ((unsigned)bin > b) sh += vsum[bin];
    }
    for (int off = 1; off < 64; off <<= 1) sh += __shfl_xor(sh, off);
    if ((t & 63) == 0) wred[t >> 6] = sh;
    __syncthreads();
    *out_bin = b;
    *out_k = *bck;
    *out_sum = wred[0] + wred[1] + wred[2] + wred[3];
}

__global__ __launch_bounds__(256) void kFused(const float* __restrict__ ploc,
                                              const float* __restrict__ plabel,
                                              const float* __restrict__ gloc,
                                              const int* __restrict__ glabel,
                                              char* __restrict__ ws,
                                              float* __restrict__ out) {
    __shared__ __align__(16) float stage[4 * 1296];  // 4 waves * 16 rows * 81
    __shared__ unsigned lh[2048];
    __shared__ float    lv[2048];
    __shared__ unsigned ssum[256];
    __shared__ float    rf[4][3];
    __shared__ float    wred[4];
    __shared__ unsigned bcb, bck;

    float*    con   = (float*)(ws + CON_B);
    unsigned* histR = (unsigned*)(ws + HISTR_B);
    float*    vsumR = (float*)(ws + VSUMR_B);
    unsigned* h1c   = (unsigned*)(ws + H1C_B);
    float*    h1v   = (float*)(ws + H1V_B);
    unsigned* h2    = (unsigned*)(ws + H2_B);
    float4*   part  = (float4*)(ws + PART_B);
    GScal*    G     = (GScal*)(ws + G_B);

    cg::grid_group grid = cg::this_grid();
    const int tid  = threadIdx.x;
    const int w    = tid >> 6;
    const int lane = tid & 63;
    const int g    = lane >> 2;
    const int l    = lane & 3;
    const int bid  = blockIdx.x;
    const int rep  = bid & (NREP - 1);

    for (int i = tid; i < 2048; i += 256) { lh[i] = 0u; lv[i] = 0.f; }
    __syncthreads();

    // ================= Phase A: CE + smoothL1 + con_neg + private hist =====
    float acc_l = 0.f, acc_c = 0.f, acc_p = 0.f;
    for (int tile = bid; tile < NTILES; tile += NBLK) {
        const size_t wrow0 = (size_t)tile * 64 + (size_t)w * 16;
        const char*  gsrc  = (const char*)(plabel + wrow0 * 81);
        char*        ldst  = (char*)&stage[w * 1296];
#pragma unroll
        for (int j = 0; j < 5; ++j)
            GLLDS16(gsrc + (size_t)j * 1024 + (size_t)lane * 16, ldst + j * 1024);
        if (lane < 4)
            GLLDS16(gsrc + 5120 + (size_t)lane * 16, ldst + 5120);

        const size_t row = wrow0 + g;
        const float pl = ploc[wrow0 * 4 + lane];
        const float gl = gloc[wrow0 * 4 + lane];
        int gt = 0;
        if (l == 0) gt = glabel[row];
        const int mask = gt > 0;

        float s = smooth_l1(pl - gl);
        s += __shfl_xor(s, 1);
        s += __shfl_xor(s, 2);

        __syncthreads();   // staging (vmcnt) drained

        const float* rowp = &stage[w * 1296 + g * 81];
        float v[20];
        float m = -INFINITY;
#pragma unroll
        for (int j = 0; j < 20; ++j) { v[j] = rowp[j * 4 + l]; m = fmaxf(m, v[j]); }
        float v80 = 0.0f;
        if (l == 0) { v80 = rowp[80]; m = fmaxf(m, v80); }
        m = fmaxf(m, __shfl_xor(m, 1));
        m = fmaxf(m, __shfl_xor(m, 2));

        float e = 0.0f;
#pragma unroll
        for (int j = 0; j < 20; ++j) e += __expf(v[j] - m);
        if (l == 0) e += __expf(v80 - m);
        e += __shfl_xor(e, 1);
        e += __shfl_xor(e, 2);
        const float lse = m + __logf(e);

        if (l == 0) {
            const float x_gt   = rowp[gt];
            const float loss_c = lse - x_gt;
            const float cn     = mask ? 0.0f : fmaxf(loss_c, 0.0f);
            con[row] = cn;
            const unsigned bin = __float_as_uint(cn) >> 21;
            atomicAdd(&lh[bin], 1u);
            if (cn != 0.0f) atomicAdd(&lv[bin], cn);
            if (mask) { acc_l += s; acc_c += loss_c; acc_p += 1.0f; }
        }
        __syncthreads();   // protect stage reuse next tile
    }

    // per-block scalar partials
    {
        float wl = acc_l, wc = acc_c, wp = acc_p;
        for (int off = 1; off < 64; off <<= 1) {
            wl += __shfl_xor(wl, off); wc += __shfl_xor(wc, off); wp += __shfl_xor(wp, off);
        }
        if (lane == 0) { rf[w][0] = wl; rf[w][1] = wc; rf[w][2] = wp; }
        __syncthreads();
        if (tid == 0)
            part[bid] = make_float4(rf[0][0] + rf[1][0] + rf[2][0] + rf[3][0],
                                    rf[0][1] + rf[1][1] + rf[2][1] + rf[3][1],
                                    rf[0][2] + rf[1][2] + rf[2][2] + rf[3][2], 0.f);
    }
    // merge private hist into replicated global hist (spread contention)
    for (int i = tid; i < 2048; i += 256) {
        const unsigned c = lh[i];
        if (c) atomicAdd(&histR[rep * 2048 + i], c);
        const float vv = lv[i];
        if (vv != 0.f) atomicAdd(&vsumR[rep * 2048 + i], vv);
    }
    __threadfence();
    grid.sync();   // S1

    // ================= R0 (block 0): scalars + level-0 select ==============
    unsigned pn = 0, b0 = 0, k1 = 0, b1 = 0, k2 = 0;
    float lossl = 0.f, poslc = 0.f, sumhi0 = 0.f, sumhi1 = 0.f;
    if (bid == 0) {
        float sl = 0.f, sc2 = 0.f, sp = 0.f;
        for (int i = tid; i < NBLK; i += 256) {
            const float4 p = part[i];
            sl += p.x; sc2 += p.y; sp += p.z;
        }
        for (int off = 1; off < 64; off <<= 1) {
            sl += __shfl_xor(sl, off); sc2 += __shfl_xor(sc2, off); sp += __shfl_xor(sp, off);
        }
        if (lane == 0) { rf[w][0] = sl; rf[w][1] = sc2; rf[w][2] = sp; }
        __syncthreads();
        lossl = rf[0][0] + rf[1][0] + rf[2][0] + rf[3][0];
        poslc = rf[0][1] + rf[1][1] + rf[2][1] + rf[3][1];
        pn = (unsigned)(rf[0][2] + rf[1][2] + rf[2][2] + rf[3][2] + 0.5f);
        for (int i = tid; i < 2048; i += 256) {
            unsigned c = 0; float vv = 0.f;
#pragma unroll
            for (int r2 = 0; r2 < NREP; ++r2) { c += histR[r2 * 2048 + i]; vv += vsumR[r2 * 2048 + i]; }
            lh[i] = c; lv[i] = vv;
        }
        __syncthreads();
        unsigned k0 = 3u * pn;
        if (k0 > (unsigned)M_TOTAL) k0 = (unsigned)M_TOTAL;
        selectk(lh, lv, 2048, k0, ssum, wred, &bcb, &bck, &b0, &k1, &sumhi0);
        if (tid == 0) g_store_u(&G->b0, b0);
    }
    __threadfence();
    grid.sync();   // S2

    // ================= H1 (all blocks): level-1 hist of bucket b0 ==========
    {
        const unsigned b0g = g_load_u(&G->b0);
        const int i = bid * 256 + tid;
        if (i < M_TOTAL / 4) {
            const float4 q = ((const float4*)con)[i];
            const float xs[4] = {q.x, q.y, q.z, q.w};
#pragma unroll
            for (int j = 0; j < 4; ++j) {
                const unsigned u = __float_as_uint(xs[j]);
                if ((u >> 21) == b0g) {
                    const unsigned mid = (u >> 10) & 0x7FFu;
                    atomicAdd(&h1c[rep * 2048 + mid], 1u);
                    atomicAdd(&h1v[rep * 2048 + mid], xs[j]);
                }
            }
        }
    }
    __threadfence();
    grid.sync();   // S3

    // ================= R1 (block 0): level-1 select ========================
    if (bid == 0) {
        for (int i = tid; i < 2048; i += 256) {
            unsigned c = 0; float vv = 0.f;
#pragma unroll
            for (int r2 = 0; r2 < NREP; ++r2) { c += h1c[r2 * 2048 + i]; vv += h1v[r2 * 2048 + i]; }
            lh[i] = c; lv[i] = vv;
        }
        __syncthreads();
        selectk(lh, lv, 2048, k1, ssum, wred, &bcb, &bck, &b1, &k2, &sumhi1);
        if (tid == 0) g_store_u(&G->pref, (b0 << 11) | b1);
    }
    __threadfence();
    grid.sync();   // S4

    // ================= H2 (all blocks): exact low-10-bit hist ==============
    {
        const unsigned prefg = g_load_u(&G->pref);
        const int i = bid * 256 + tid;
        if (i < M_TOTAL / 4) {
            const float4 q = ((const float4*)con)[i];
            const float xs[4] = {q.x, q.y, q.z, q.w};
#pragma unroll
            for (int j = 0; j < 4; ++j) {
                const unsigned u = __float_as_uint(xs[j]);
                if ((u >> 10) == prefg) atomicAdd(&h2[u & 0x3FFu], 1u);
            }
        }
    }
    __threadfence();
    grid.sync();   // S5

    // ================= R2 (block 0): final select + output =================
    if (bid == 0) {
        const unsigned pref = (b0 << 11) | b1;
        for (int i = tid; i < 1024; i += 256) {
            const unsigned c = h2[i];
            lh[i] = c;
            lv[i] = c ? (float)c * __uint_as_float((pref << 10) | (unsigned)i) : 0.f;
        }
        __syncthreads();
        unsigned ct, r; float sumhi2;
        selectk(lh, lv, 1024, k2, ssum, wred, &bcb, &bck, &ct, &r, &sumhi2);
        if (tid == 0) {
            float outv = 0.f;
            if (pn > 0u) {
                const float tval  = __uint_as_float((pref << 10) | ct);
                const float closs = poslc + sumhi0 + sumhi1 + sumhi2 + (float)r * tval;
                outv = (lossl + closs) / (float)pn;
            }
            out[0] = outv;
        }
    }
}

extern "C" void kernel_launch(void* const* d_in, const int* in_sizes, int n_in,
                              void* d_out, int out_size, void* d_ws, size_t ws_size,
                              hipStream_t stream) {
    const float* ploc   = (const float*)d_in[0];
    const float* plabel = (const float*)d_in[1];
    const float* gloc   = (const float*)d_in[2];
    const int*   glabel = (const int*)d_in[3];
    float* out = (float*)d_out;
    char*  ws  = (char*)d_ws;

    // zero hist replicas + h2 + partials + G
    const size_t zero_bytes = (G_B - HISTR_B) + sizeof(GScal);
    hipMemsetAsync(ws + HISTR_B, 0, zero_bytes, stream);

    void* args[] = {(void*)&ploc, (void*)&plabel, (void*)&gloc,
                    (void*)&glabel, (void*)&ws, (void*)&out};
    hipLaunchCooperativeKernel((const void*)kFused, dim3(NBLK), dim3(256), args, 0, stream);
}

// Round 4
// 181.437 us; speedup vs baseline: 3.3262x; 3.3262x over previous
//
#include <hip/hip_runtime.h>
#include <math.h>

#define M_TOTAL (32 * 8732)        // 279424 anchors
#define NBLK_A  (M_TOTAL / 64)     // 4366 blocks, 64 anchors each
#define NREP    32                 // hist replication (breaks same-line atomic serialization)
#define NH1     273                // ceil((M_TOTAL/4)/256) for float4 passes

// ---- workspace layout (bytes), all 16B-aligned ----
#define CON_B    ((size_t)0)                         // M floats
#define HISTR_B  ((size_t)M_TOTAL * 4)               // NREP*2048 u32
#define H1_B     (HISTR_B + (size_t)NREP * 2048 * 4) // 2048 u32
#define H2_B     (H1_B + (size_t)2048 * 4)           // 1024 u32
#define G_B      (H2_B + (size_t)1024 * 4)           // scalars (64 B reserved)
#define PART_B   (G_B + 64)                          // NBLK_A float4 (fully written, no zero)
#define ZERO_BYTES ((H2_B + 1024 * 4 + 64) - HISTR_B)

struct GS {
    unsigned pn;
    float    lossl;
    float    poslc;
    unsigned b0;
    unsigned k1;
    unsigned pref;   // (b0<<11)|b1
    unsigned k2;
    float    sumhi0; // sum of con where (u>>21)  > b0
    float    sumhi1; // sum of con where (u>>21) == b0 && mid > b1
};

__device__ __forceinline__ float smooth_l1(float d) {
    float ad = fabsf(d);
    return (ad < 1.0f) ? 0.5f * ad * ad : ad - 0.5f;
}

#define GLLDS16(gp, lp) __builtin_amdgcn_global_load_lds( \
    (__attribute__((address_space(1))) void*)(gp),        \
    (__attribute__((address_space(3))) void*)(lp), 16, 0, 0)

// ---- kA: CE + smoothL1 + con_neg + replicated level-0 histogram ----
__global__ __launch_bounds__(256) void kA(const float* __restrict__ ploc,
                                          const float* __restrict__ plabel,
                                          const float* __restrict__ gloc,
                                          const int* __restrict__ glabel,
                                          float* __restrict__ con,
                                          unsigned* __restrict__ histR,
                                          float4* __restrict__ part) {
    __shared__ __align__(16) float stage[4 * 1296];  // 4 waves * 16 rows * 81 floats
    __shared__ unsigned lh[2048];
    __shared__ float    rf[4][3];

    const int tid  = threadIdx.x;
    const int w    = tid >> 6;
    const int lane = tid & 63;
    const int g    = lane >> 2;
    const int l    = lane & 3;

    for (int i = tid; i < 2048; i += 256) lh[i] = 0u;

    const size_t wrow0 = (size_t)blockIdx.x * 64 + (size_t)w * 16;
    const char*  gsrc  = (const char*)(plabel + wrow0 * 81);
    char*        ldst  = (char*)&stage[w * 1296];
#pragma unroll
    for (int j = 0; j < 5; ++j)
        GLLDS16(gsrc + (size_t)j * 1024 + (size_t)lane * 16, ldst + j * 1024);
    if (lane < 4)
        GLLDS16(gsrc + 5120 + (size_t)lane * 16, ldst + 5120);

    const size_t row = wrow0 + g;
    const float pl = ploc[wrow0 * 4 + lane];
    const float gl = gloc[wrow0 * 4 + lane];
    int gt = 0;
    if (l == 0) gt = glabel[row];
    const int mask = gt > 0;

    float s = smooth_l1(pl - gl);
    s += __shfl_xor(s, 1);
    s += __shfl_xor(s, 2);

    __syncthreads();   // drains global_load_lds (vmcnt) + lh zero visible

    const float* rowp = &stage[w * 1296 + g * 81];
    float v[20];
    float m = -INFINITY;
#pragma unroll
    for (int j = 0; j < 20; ++j) { v[j] = rowp[j * 4 + l]; m = fmaxf(m, v[j]); }
    float v80 = 0.0f;
    if (l == 0) { v80 = rowp[80]; m = fmaxf(m, v80); }
    m = fmaxf(m, __shfl_xor(m, 1));
    m = fmaxf(m, __shfl_xor(m, 2));

    float e = 0.0f;
#pragma unroll
    for (int j = 0; j < 20; ++j) e += __expf(v[j] - m);
    if (l == 0) e += __expf(v80 - m);
    e += __shfl_xor(e, 1);
    e += __shfl_xor(e, 2);
    const float lse = m + __logf(e);

    float wl = 0.f, wc = 0.f, wp = 0.f;
    if (l == 0) {
        const float x_gt   = rowp[gt];
        const float loss_c = lse - x_gt;
        const float cn     = mask ? 0.0f : fmaxf(loss_c, 0.0f);
        con[row] = cn;
        atomicAdd(&lh[__float_as_uint(cn) >> 21], 1u);   // LDS atomic: cheap
        if (mask) { wl = s; wc = loss_c; wp = 1.0f; }
    }
#pragma unroll
    for (int off = 4; off < 64; off <<= 1) {
        wl += __shfl_xor(wl, off);
        wc += __shfl_xor(wc, off);
        wp += __shfl_xor(wp, off);
    }
    if (lane == 0) { rf[w][0] = wl; rf[w][1] = wc; rf[w][2] = wp; }
    __syncthreads();   // lh atomics done; rf visible

    if (tid == 0)      // plain store — NO contended device atomics for scalars
        part[blockIdx.x] = make_float4(rf[0][0] + rf[1][0] + rf[2][0] + rf[3][0],
                                       rf[0][1] + rf[1][1] + rf[2][1] + rf[3][1],
                                       rf[0][2] + rf[1][2] + rf[2][2] + rf[3][2], 0.f);

    unsigned* hrep = histR + (size_t)(blockIdx.x & (NREP - 1)) * 2048;
    for (int i = tid; i < 2048; i += 256) {
        const unsigned c = lh[i];
        if (c) atomicAdd(&hrep[i], c);
    }
}

// ---- suffix-select over nbins (<=2048) with 1024 threads ----
// finds bin with suffix(bin) >= k > suffix(bin+1); results in *pbin,*pk (k==0 -> 0,0)
__device__ void suffix_select(const unsigned* h, int nbins, unsigned k,
                              unsigned* ssum, unsigned* pbin, unsigned* pk) {
    const int t = threadIdx.x;
    if (t == 0) { *pbin = 0u; *pk = 0u; }
    const unsigned h0 = (2 * t     < nbins) ? h[2 * t]     : 0u;
    const unsigned h1 = (2 * t + 1 < nbins) ? h[2 * t + 1] : 0u;
    ssum[t] = h0 + h1;
    __syncthreads();
    for (int off = 1; off < 1024; off <<= 1) {
        const unsigned val = ssum[t];
        const unsigned add = (t + off < 1024) ? ssum[t + off] : 0u;
        __syncthreads();
        ssum[t] = val + add;
        __syncthreads();
    }
    const unsigned sA = ssum[t];
    const unsigned sB = sA - h0;
    const unsigned sC = (t + 1 < 1024) ? ssum[t + 1] : 0u;
    if (k > 0u) {
        if (2 * t < nbins && sA >= k && k > sB) { *pbin = 2u * (unsigned)t;      *pk = k - sB; }
        if (2 * t + 1 < nbins && sB >= k && k > sC) { *pbin = 2u * (unsigned)t + 1u; *pk = k - sC; }
    }
    __syncthreads();
}

// ---- kR0: fold replicated hist + reduce part[] + level-0 select ----
__global__ __launch_bounds__(1024) void kR0(const unsigned* __restrict__ histR,
                                            const float4* __restrict__ part,
                                            GS* __restrict__ G) {
    __shared__ unsigned lh[2048];
    __shared__ unsigned ssum[1024];
    __shared__ float    rf3[16][3];
    __shared__ unsigned sbin, sk;
    const int t = threadIdx.x;

    for (int b = t; b < 2048; b += 1024) {
        unsigned c = 0;
#pragma unroll
        for (int r = 0; r < NREP; ++r) c += histR[r * 2048 + b];
        lh[b] = c;
    }

    float sl = 0.f, sc = 0.f, sp = 0.f;
    for (int i = t; i < NBLK_A; i += 1024) {
        const float4 p = part[i];
        sl += p.x; sc += p.y; sp += p.z;
    }
#pragma unroll
    for (int off = 1; off < 64; off <<= 1) {
        sl += __shfl_xor(sl, off); sc += __shfl_xor(sc, off); sp += __shfl_xor(sp, off);
    }
    if ((t & 63) == 0) { rf3[t >> 6][0] = sl; rf3[t >> 6][1] = sc; rf3[t >> 6][2] = sp; }
    __syncthreads();

    float tsl = 0.f, tsc = 0.f, tsp = 0.f;
    for (int i = 0; i < 16; ++i) { tsl += rf3[i][0]; tsc += rf3[i][1]; tsp += rf3[i][2]; }
    const unsigned pn = (unsigned)(tsp + 0.5f);
    unsigned k0 = 3u * pn;
    if (k0 > (unsigned)M_TOTAL) k0 = (unsigned)M_TOTAL;

    suffix_select(lh, 2048, k0, ssum, &sbin, &sk);
    if (t == 0) {
        G->pn = pn; G->lossl = tsl; G->poslc = tsc;
        G->b0 = sbin; G->k1 = sk;
    }
}

// ---- kH1: level-1 hist of bucket b0 + sum of strictly-above buckets ----
__global__ __launch_bounds__(256) void kH1(const float4* __restrict__ con4,
                                           unsigned* __restrict__ h1,
                                           GS* __restrict__ G) {
    __shared__ float wred[4];
    const unsigned b0 = G->b0;
    const int i = blockIdx.x * 256 + threadIdx.x;
    float s = 0.f;
    if (i < M_TOTAL / 4) {
        const float4 q = con4[i];
        const float xs[4] = {q.x, q.y, q.z, q.w};
#pragma unroll
        for (int j = 0; j < 4; ++j) {
            const unsigned u  = __float_as_uint(xs[j]);
            const unsigned hi = u >> 21;
            if (hi > b0) s += xs[j];
            else if (hi == b0) atomicAdd(&h1[(u >> 10) & 0x7FFu], 1u);  // ~7k ops / 2048 bins: uncontended
        }
    }
#pragma unroll
    for (int off = 1; off < 64; off <<= 1) s += __shfl_xor(s, off);
    if ((threadIdx.x & 63) == 0) wred[threadIdx.x >> 6] = s;
    __syncthreads();
    if (threadIdx.x == 0) {
        const float tot = wred[0] + wred[1] + wred[2] + wred[3];
        if (tot != 0.f) atomicAdd(&G->sumhi0, tot);   // 273 same-address atomics: ~1 µs
    }
}

// ---- kR1: level-1 select ----
__global__ __launch_bounds__(1024) void kR1(const unsigned* __restrict__ h1,
                                            GS* __restrict__ G) {
    __shared__ unsigned ssum[1024];
    __shared__ unsigned sbin, sk;
    const unsigned k1 = G->k1;
    suffix_select(h1, 2048, k1, ssum, &sbin, &sk);
    if (threadIdx.x == 0) {
        G->pref = (G->b0 << 11) | sbin;
        G->k2   = sk;
    }
}

// ---- kH2: exact low-10-bit hist within (b0,b1) + mid-level above-sum ----
__global__ __launch_bounds__(256) void kH2(const float4* __restrict__ con4,
                                           unsigned* __restrict__ h2,
                                           GS* __restrict__ G) {
    __shared__ float wred[4];
    const unsigned pref = G->pref;
    const unsigned b0 = pref >> 11, b1 = pref & 0x7FFu;
    const int i = blockIdx.x * 256 + threadIdx.x;
    float s = 0.f;
    if (i < M_TOTAL / 4) {
        const float4 q = con4[i];
        const float xs[4] = {q.x, q.y, q.z, q.w};
#pragma unroll
        for (int j = 0; j < 4; ++j) {
            const unsigned u = __float_as_uint(xs[j]);
            if ((u >> 21) == b0) {
                const unsigned mid = (u >> 10) & 0x7FFu;
                if (mid > b1) s += xs[j];
                else if (mid == b1) atomicAdd(&h2[u & 0x3FFu], 1u);  // ~tens of ops
            }
        }
    }
#pragma unroll
    for (int off = 1; off < 64; off <<= 1) s += __shfl_xor(s, off);
    if ((threadIdx.x & 63) == 0) wred[threadIdx.x >> 6] = s;
    __syncthreads();
    if (threadIdx.x == 0) {
        const float tot = wred[0] + wred[1] + wred[2] + wred[3];
        if (tot != 0.f) atomicAdd(&G->sumhi1, tot);
    }
}

// ---- kR2: final select (bin == exact bit pattern) + output ----
__global__ __launch_bounds__(1024) void kR2(const unsigned* __restrict__ h2,
                                            const GS* __restrict__ G,
                                            float* __restrict__ out) {
    __shared__ unsigned lh[1024];
    __shared__ unsigned ssum[1024];
    __shared__ unsigned sbin, sk;
    __shared__ float    wred[16];
    const int t = threadIdx.x;
    const unsigned k2   = G->k2;
    const unsigned pref = G->pref;

    const unsigned c = h2[t];
    lh[t] = c;
    __syncthreads();
    suffix_select(lh, 1024, k2, ssum, &sbin, &sk);
    const unsigned ct = sbin, r = sk;

    float s = 0.f;
    if ((unsigned)t > ct && c)
        s = (float)c * __uint_as_float((pref << 10) | (unsigned)t);
#pragma unroll
    for (int off = 1; off < 64; off <<= 1) s += __shfl_xor(s, off);
    if ((t & 63) == 0) wred[t >> 6] = s;
    __syncthreads();

    if (t == 0) {
        float sumhi2 = 0.f;
        for (int i = 0; i < 16; ++i) sumhi2 += wred[i];
        const unsigned pn = G->pn;
        float outv = 0.f;
        if (pn > 0u) {
            const float tval  = __uint_as_float((pref << 10) | ct);
            const float closs = G->poslc + G->sumhi0 + G->sumhi1 + sumhi2 + (float)r * tval;
            outv = (G->lossl + closs) / (float)pn;
        }
        out[0] = outv;
    }
}

extern "C" void kernel_launch(void* const* d_in, const int* in_sizes, int n_in,
                              void* d_out, int out_size, void* d_ws, size_t ws_size,
                              hipStream_t stream) {
    const float* ploc   = (const float*)d_in[0];
    const float* plabel = (const float*)d_in[1];
    const float* gloc   = (const float*)d_in[2];
    const int*   glabel = (const int*)d_in[3];
    float* out = (float*)d_out;
    char*  ws  = (char*)d_ws;

    float*    con   = (float*)(ws + CON_B);
    unsigned* histR = (unsigned*)(ws + HISTR_B);
    unsigned* h1    = (unsigned*)(ws + H1_B);
    unsigned* h2    = (unsigned*)(ws + H2_B);
    GS*       G     = (GS*)(ws + G_B);
    float4*   part  = (float4*)(ws + PART_B);

    hipMemsetAsync(ws + HISTR_B, 0, ZERO_BYTES, stream);   // histR + h1 + h2 + G

    kA <<<NBLK_A, 256, 0, stream>>>(ploc, plabel, gloc, glabel, con, histR, part);
    kR0<<<1, 1024, 0, stream>>>(histR, part, G);
    kH1<<<NH1, 256, 0, stream>>>((const float4*)con, h1, G);
    kR1<<<1, 1024, 0, stream>>>(h1, G);
    kH2<<<NH1, 256, 0, stream>>>((const float4*)con, h2, G);
    kR2<<<1, 1024, 0, stream>>>(h2, G, out);
}